// Round 2
// baseline (1889.421 us; speedup 1.0000x reference)
//
#include <hip/hip_runtime.h>

// Conv: out = (norm * (x + segment_sum(x[sources], targets))) @ W
// N = 100000, E = 4000000, C = 64, fp32.
// Pipeline: prep (fused x->bf16 cvt + bucket hist) -> tiny scan -> bin v3
// (8K-chunk LDS-staged dense-run bucket sort) -> sortgather.
// NOTE: fp8 gather tried in R9 -> absmax 0.875 > 0.65 threshold. bf16 is the
// floor precision (absmax 0.125, 5x margin). Self term exact fp32.
// R10: 512 threads -> NEUTRAL (170us). Occupancy stuck ~8-9 waves/CU in both
// configs, throughput insensitive to wave count => per-CU outstanding-line
// (MSHR) saturation at LLC-ish latency (~8KB in flight/CU @ ~650ns).
// R11: locality restructure. Accumulate into LDS fp32 accum[128x64] via
// ds_add_f32 (order-free), re-key the block-local counting sort from
// target-node to SOURCE RANGE (src>>10). All blocks walk sources in ascending
// order in near-lockstep => machine-wide active xb window ~0.5-2MB, fits
// per-XCD 4MB L2 => gather latency ~3x lower => ~3x gather BW at same MSHR
// depth. accum rows stride-65 (bank rotation by target) to keep ds_add ~2-way.

constexpr int C = 64;
constexpr int BN = 128;       // nodes per bucket
constexpr int CHUNK2 = 8192;  // edges per hist/bin block (512 threads)
constexpr int MAXB = 1024;    // LDS bucket arrays capacity (NB = 782)
constexpr int CAP = 6144;     // LDS sort staging (bucket avg 5120, max ~5400)
constexpr int RB = 128;       // source-range bins (src>>10 -> 0..97)
constexpr int ASTRIDE = 65;   // accum row stride (bank-rotation swizzle)

// --- 1. fused: x -> bf16 (RNE)  +  bucket histogram -------------------------
__global__ __launch_bounds__(512) void prep_kernel(
    const float* __restrict__ x, unsigned* __restrict__ xb,
    const int* __restrict__ tgt, int* __restrict__ bhist,
    int E, int NB, int histBlocks, int total8) {
  __shared__ int h[MAXB];
  if ((int)blockIdx.x < histBlocks) {
    for (int i = threadIdx.x; i < NB; i += 512) h[i] = 0;
    __syncthreads();
    int base = blockIdx.x * CHUNK2;
    int end = base + CHUNK2; if (end > E) end = E;
    for (int i = base + threadIdx.x; i < end; i += 512)
      atomicAdd(&h[tgt[i] >> 7], 1);
    __syncthreads();
    for (int i = threadIdx.x; i < NB; i += 512)
      if (h[i]) atomicAdd(&bhist[i], h[i]);
  } else {
    int i = (blockIdx.x - histBlocks) * 512 + threadIdx.x;  // 8 floats each
    if (i < total8) {
      const float4* x4 = (const float4*)x;
      float4 a = x4[i * 2], bq = x4[i * 2 + 1];
      float f[8] = {a.x, a.y, a.z, a.w, bq.x, bq.y, bq.z, bq.w};
      unsigned w[4];
#pragma unroll
      for (int k = 0; k < 4; k++) {
        unsigned u0 = __float_as_uint(f[2 * k]);
        unsigned u1 = __float_as_uint(f[2 * k + 1]);
        u0 = (u0 + 0x7FFFu + ((u0 >> 16) & 1u)) >> 16;
        u1 = (u1 + 0x7FFFu + ((u1 >> 16) & 1u)) >> 16;
        w[k] = u0 | (u1 << 16);
      }
      ((uint4*)xb)[i] = make_uint4(w[0], w[1], w[2], w[3]);
    }
  }
}

// --- 2. scan of NB bucket counts (1 block) ----------------------------------
__global__ __launch_bounds__(256) void bscan_kernel(
    const int* __restrict__ bhist, int* __restrict__ bbase,
    int* __restrict__ cursor, int NB) {
  __shared__ int partials[256];
  int tid = threadIdx.x;
  int per = (NB + 255) / 256;
  int lo = tid * per, hi = lo + per;
  if (lo > NB) lo = NB;
  if (hi > NB) hi = NB;
  int s = 0;
  for (int i = lo; i < hi; i++) s += bhist[i];
  partials[tid] = s;
  __syncthreads();
  for (int off = 1; off < 256; off <<= 1) {
    int v = partials[tid];
    int a = (tid >= off) ? partials[tid - off] : 0;
    __syncthreads();
    partials[tid] = v + a;
    __syncthreads();
  }
  int run = partials[tid] - s;
  for (int i = lo; i < hi; i++) { bbase[i] = run; cursor[i] = run; run += bhist[i]; }
  if (tid == 255) bbase[NB] = partials[255];
}

// --- 3. bin v3: 8K chunks, LDS staging, dense ~10.5-rec runs ----------------
__global__ __launch_bounds__(512) void bin_kernel(
    const int* __restrict__ src, const int* __restrict__ tgt,
    int* __restrict__ gcursor, unsigned* __restrict__ recs, int E, int NB) {
  __shared__ unsigned rec[CHUNK2];        // 32 KB
  __shared__ unsigned short bkt[CHUNK2];  // 16 KB
  __shared__ int hist[MAXB];              // 4 KB
  __shared__ int gb[MAXB];                // 4 KB
  int tid = threadIdx.x;
  int base = blockIdx.x * CHUNK2;
  int count = E - base; if (count > CHUNK2) count = CHUNK2;

  for (int i = tid; i < NB; i += 512) hist[i] = 0;
  __syncthreads();
  for (int i = tid; i < count; i += 512) {
    int s = src[base + i], t = tgt[base + i];
    int b = t >> 7;
    rec[i] = ((unsigned)s << 7) | (unsigned)(t & 127);
    bkt[i] = (unsigned short)b;
    atomicAdd(&hist[b], 1);
  }
  __syncthreads();
  for (int i = tid; i < NB; i += 512) {
    int c = hist[i];
    gb[i] = c ? atomicAdd(&gcursor[i], c) : 0;
  }
  __syncthreads();
  for (int i = tid; i < NB; i += 512) hist[i] = 0;
  __syncthreads();
  for (int i = tid; i < count; i += 512) {
    int b = (int)bkt[i];
    int idx = atomicAdd(&hist[b], 1);
    recs[gb[b] + idx] = rec[i];
  }
}

// --- 4. fused sort + gather + scale + matmul --------------------------------
// One block per bucket, 8 waves. Edges sorted by SOURCE RANGE (src>>10) so
// all blocks walk sources in ascending order (L2-resident window). Edge
// contributions go into LDS fp32 accum via ds_add_f32; epilogue does
// broadcast-read matmul. Self term init'd exact fp32.
template <bool USE_BF16>
__global__ __launch_bounds__(512) void sortgather_kernel(
    const float* __restrict__ x, const unsigned* __restrict__ xb,
    const unsigned* __restrict__ recs, const int* __restrict__ bbase,
    const float* __restrict__ norm, const float* __restrict__ W,
    float* __restrict__ out, int N) {
  __shared__ int cnt[RB];
  __shared__ int pre[RB];
  __shared__ unsigned sorted[CAP];      // 24 KB (full records)
  __shared__ float accum[BN * ASTRIDE]; // 32.5 KB, stride-65 bank rotation
  int tid = threadIdx.x;
  int lane = tid & 63;
  int wave = tid >> 6;  // 0..7
  int b = blockIdx.x;
  int n0 = b * BN;
  int nn = N - n0; if (nn > BN) nn = BN;
  int beg = bbase[b], end = bbase[b + 1];
  int m = end - beg;

  float wreg[C];
#pragma unroll
  for (int k = 0; k < C; k++) wreg[k] = W[k * C + lane];

  // init accum with exact fp32 self term
  for (int i = tid; i < nn * C; i += 512) {
    int node = i >> 6, c = i & 63;
    accum[node * ASTRIDE + c] = x[(n0 + node) * C + c];
  }

  // counting sort by source range into LDS
  if (tid < RB) cnt[tid] = 0;
  __syncthreads();
  for (int r = beg + tid; r < end; r += 512)
    atomicAdd(&cnt[recs[r] >> 17], 1);  // key = src >> 10
  __syncthreads();
  if (tid < RB) pre[tid] = cnt[tid];
  __syncthreads();
  for (int off = 1; off < RB; off <<= 1) {
    int v = 0, a = 0;
    if (tid < RB) { v = pre[tid]; a = (tid >= off) ? pre[tid - off] : 0; }
    __syncthreads();
    if (tid < RB) pre[tid] = v + a;
    __syncthreads();
  }
  if (tid < RB) cnt[tid] = pre[tid] - cnt[tid];  // exclusive prefix -> cursor
  __syncthreads();
  bool fits = (m <= CAP);
  if (fits) {
    for (int r = beg + tid; r < end; r += 512) {
      unsigned rc = recs[r];
      int p = atomicAdd(&cnt[rc >> 17], 1);
      sorted[p] = rc;
    }
  }
  __syncthreads();

  int sub, grp;
  if (USE_BF16) { sub = lane & 7;  grp = lane >> 3; }   // 8 edges/wave-iter
  else          { sub = lane & 15; grp = lane >> 4; }   // 4 edges/wave-iter
  const float4* x4 = (const float4*)x;
  const uint4* xb4 = (const uint4*)xb;  // bf16 row = 8 uint4 (128 B)

  if (USE_BF16) {
    // 2 edge slots deep per iteration (2 loads in flight per lane)
    if (fits) {
      for (int e0 = wave * 16; e0 < m; e0 += 128) {
        int eA = e0 + grp, eB = e0 + 8 + grp;
        unsigned rcA = 0, rcB = 0; uint4 vA, vB;
        bool okA = eA < m, okB = eB < m;
        if (okA) { rcA = sorted[eA]; vA = xb4[(rcA >> 7) * 8 + sub]; }
        if (okB) { rcB = sorted[eB]; vB = xb4[(rcB >> 7) * 8 + sub]; }
        if (okA) {
          float* a = &accum[(int)(rcA & 127u) * ASTRIDE + sub * 8];
          atomicAdd(&a[0], __uint_as_float(vA.x << 16));
          atomicAdd(&a[1], __uint_as_float(vA.x & 0xFFFF0000u));
          atomicAdd(&a[2], __uint_as_float(vA.y << 16));
          atomicAdd(&a[3], __uint_as_float(vA.y & 0xFFFF0000u));
          atomicAdd(&a[4], __uint_as_float(vA.z << 16));
          atomicAdd(&a[5], __uint_as_float(vA.z & 0xFFFF0000u));
          atomicAdd(&a[6], __uint_as_float(vA.w << 16));
          atomicAdd(&a[7], __uint_as_float(vA.w & 0xFFFF0000u));
        }
        if (okB) {
          float* a = &accum[(int)(rcB & 127u) * ASTRIDE + sub * 8];
          atomicAdd(&a[0], __uint_as_float(vB.x << 16));
          atomicAdd(&a[1], __uint_as_float(vB.x & 0xFFFF0000u));
          atomicAdd(&a[2], __uint_as_float(vB.y << 16));
          atomicAdd(&a[3], __uint_as_float(vB.y & 0xFFFF0000u));
          atomicAdd(&a[4], __uint_as_float(vB.z << 16));
          atomicAdd(&a[5], __uint_as_float(vB.z & 0xFFFF0000u));
          atomicAdd(&a[6], __uint_as_float(vB.w << 16));
          atomicAdd(&a[7], __uint_as_float(vB.w & 0xFFFF0000u));
        }
      }
    } else {  // overflow fallback (statistically unreachable): unsorted global
      for (int r0 = beg + wave * 8; r0 < end; r0 += 64) {
        int e = r0 + grp;
        if (e < end) {
          unsigned rc = recs[e];
          uint4 v = xb4[(rc >> 7) * 8 + sub];
          float* a = &accum[(int)(rc & 127u) * ASTRIDE + sub * 8];
          atomicAdd(&a[0], __uint_as_float(v.x << 16));
          atomicAdd(&a[1], __uint_as_float(v.x & 0xFFFF0000u));
          atomicAdd(&a[2], __uint_as_float(v.y << 16));
          atomicAdd(&a[3], __uint_as_float(v.y & 0xFFFF0000u));
          atomicAdd(&a[4], __uint_as_float(v.z << 16));
          atomicAdd(&a[5], __uint_as_float(v.z & 0xFFFF0000u));
          atomicAdd(&a[6], __uint_as_float(v.w << 16));
          atomicAdd(&a[7], __uint_as_float(v.w & 0xFFFF0000u));
        }
      }
    }
  } else {
    if (fits) {
      for (int e0 = wave * 8; e0 < m; e0 += 64) {
        int eA = e0 + grp, eB = e0 + 4 + grp;
        unsigned rcA = 0, rcB = 0; float4 vA, vB;
        bool okA = eA < m, okB = eB < m;
        if (okA) { rcA = sorted[eA]; vA = x4[(rcA >> 7) * 16 + sub]; }
        if (okB) { rcB = sorted[eB]; vB = x4[(rcB >> 7) * 16 + sub]; }
        if (okA) {
          float* a = &accum[(int)(rcA & 127u) * ASTRIDE + sub * 4];
          atomicAdd(&a[0], vA.x); atomicAdd(&a[1], vA.y);
          atomicAdd(&a[2], vA.z); atomicAdd(&a[3], vA.w);
        }
        if (okB) {
          float* a = &accum[(int)(rcB & 127u) * ASTRIDE + sub * 4];
          atomicAdd(&a[0], vB.x); atomicAdd(&a[1], vB.y);
          atomicAdd(&a[2], vB.z); atomicAdd(&a[3], vB.w);
        }
      }
    } else {
      for (int r0 = beg + wave * 4; r0 < end; r0 += 32) {
        int e = r0 + grp;
        if (e < end) {
          unsigned rc = recs[e];
          float4 v = x4[(rc >> 7) * 16 + sub];
          float* a = &accum[(int)(rc & 127u) * ASTRIDE + sub * 4];
          atomicAdd(&a[0], v.x); atomicAdd(&a[1], v.y);
          atomicAdd(&a[2], v.z); atomicAdd(&a[3], v.w);
        }
      }
    }
  }
  __syncthreads();

  // epilogue: out[n][lane] = norm[n] * sum_k accum[n][k] * W[k][lane]
  for (int i = wave; i < nn; i += 8) {
    int n = n0 + i;
    const float* arow = &accum[i * ASTRIDE];
    float o = 0.0f;
#pragma unroll
    for (int k = 0; k < C; k++)
      o = fmaf(arow[k], wreg[k], o);   // arow[k]: broadcast LDS read
    out[n * C + lane] = o * norm[n];
  }
}

extern "C" void kernel_launch(void* const* d_in, const int* in_sizes, int n_in,
                              void* d_out, int out_size, void* d_ws, size_t ws_size,
                              hipStream_t stream) {
  const float* x       = (const float*)d_in[0];
  const int*   sources = (const int*)d_in[1];
  const int*   targets = (const int*)d_in[2];
  const float* norm    = (const float*)d_in[3];
  const float* weight  = (const float*)d_in[4];
  float* out = (float*)d_out;

  int N = in_sizes[0] / C;     // 100000
  int E = in_sizes[1];         // 4000000
  int NB = (N + BN - 1) / BN;  // 782

  // ws (bf16): xb 12.8MB | bhist[NB] | bbase[NB+1] | cursor[NB] | recs[E] -> 28.8MB
  size_t xb_words = (size_t)N * C / 2;  // bf16 vals packed in unsigned words
  size_t meta_words = (size_t)3 * NB + 1 + (size_t)E;
  bool use_bf16 = ws_size >= (xb_words + meta_words) * 4;

  unsigned* xb; int* bhist;
  if (use_bf16) {
    xb = (unsigned*)d_ws;                 // 16B-aligned block first
    bhist = (int*)d_ws + xb_words;
  } else {
    xb = nullptr;
    bhist = (int*)d_ws;
  }
  int* bbase  = bhist + NB;
  int* cursor = bbase + (NB + 1);
  unsigned* recs = (unsigned*)(cursor + NB);

  hipMemsetAsync(bhist, 0, (size_t)NB * sizeof(int), stream);

  int hb = (E + CHUNK2 - 1) / CHUNK2;  // 489
  int total8 = N * C / 8;              // 800000
  int cvtBlocks = use_bf16 ? (total8 + 511) / 512 : 0;
  prep_kernel<<<hb + cvtBlocks, 512, 0, stream>>>(x, xb, targets, bhist, E, NB, hb, total8);
  bscan_kernel<<<1, 256, 0, stream>>>(bhist, bbase, cursor, NB);
  bin_kernel<<<hb, 512, 0, stream>>>(sources, targets, cursor, recs, E, NB);
  if (use_bf16) {
    sortgather_kernel<true><<<NB, 512, 0, stream>>>(x, xb, recs, bbase, norm, weight, out, N);
  } else {
    sortgather_kernel<false><<<NB, 512, 0, stream>>>(x, xb, recs, bbase, norm, weight, out, N);
  }
}

// Round 3
// 392.747 us; speedup vs baseline: 4.8108x; 4.8108x over previous
//
#include <hip/hip_runtime.h>

// Conv: out = (norm * (x + segment_sum(x[sources], targets))) @ W
// N = 100000, E = 4000000, C = 64, fp32.
// Pipeline: prep (fused x->bf16 cvt + bucket hist) -> tiny scan -> bin v3
// (8K-chunk LDS-staged dense-run bucket sort) -> sortgather.
// NOTE: fp8 gather tried in R9 -> absmax 0.875 > 0.65 threshold. bf16 is the
// floor precision (absmax 0.125, 5x margin). Self term exact fp32.
// R10: 512 threads -> NEUTRAL (170us): throughput insensitive to wave count.
// R11: LDS fp32 atomic accumulation -> 1742us DISASTER (E*C=256M lane-atomics,
// likely CAS/flat path). Lesson: per-edge-channel LDS accumulation is fatal;
// register accumulation is mandatory. But FETCH dropped 200->175MB => source
// ordering does improve locality.
// R12: MSHR-latency model: gather rate = MSHR(~32-40 lines/CU) * 128B /
// avg_latency. Lever = L2 hit rate (61% measured). Sort key now
// (t_local, src_window) with 3 windows of ~4.2MB xb (~ per-XCD L2). Gather in
// 3 passes (pass-outer): machine-wide active xb footprint ~1-2 windows =>
// higher hit rate => lower avg latency => faster at fixed MSHR. Register acc
// per (node,pass) + shfl reduce + ONE race-free LDS RMW instr per node-pass
// (lane (grp,sub) owns channel sub*8+grp; node rows wave-exclusive).

constexpr int C = 64;
constexpr int BN = 128;       // nodes per bucket
constexpr int CHUNK2 = 8192;  // edges per hist/bin block (512 threads)
constexpr int MAXB = 1024;    // LDS bucket arrays capacity (NB = 782)
constexpr int CAP = 6144;     // LDS sort staging (bucket avg 5120, max ~5400)
constexpr int NPASS = 3;      // source windows (src>>15 clamped to 0..2)
constexpr int BINS = BN * 4;  // (t_local, window) bins; slot 3 unused
constexpr int ASTRIDE = 65;   // accum row stride (bank rotation)

// --- 1. fused: x -> bf16 (RNE)  +  bucket histogram -------------------------
__global__ __launch_bounds__(512) void prep_kernel(
    const float* __restrict__ x, unsigned* __restrict__ xb,
    const int* __restrict__ tgt, int* __restrict__ bhist,
    int E, int NB, int histBlocks, int total8) {
  __shared__ int h[MAXB];
  if ((int)blockIdx.x < histBlocks) {
    for (int i = threadIdx.x; i < NB; i += 512) h[i] = 0;
    __syncthreads();
    int base = blockIdx.x * CHUNK2;
    int end = base + CHUNK2; if (end > E) end = E;
    for (int i = base + threadIdx.x; i < end; i += 512)
      atomicAdd(&h[tgt[i] >> 7], 1);
    __syncthreads();
    for (int i = threadIdx.x; i < NB; i += 512)
      if (h[i]) atomicAdd(&bhist[i], h[i]);
  } else {
    int i = (blockIdx.x - histBlocks) * 512 + threadIdx.x;  // 8 floats each
    if (i < total8) {
      const float4* x4 = (const float4*)x;
      float4 a = x4[i * 2], bq = x4[i * 2 + 1];
      float f[8] = {a.x, a.y, a.z, a.w, bq.x, bq.y, bq.z, bq.w};
      unsigned w[4];
#pragma unroll
      for (int k = 0; k < 4; k++) {
        unsigned u0 = __float_as_uint(f[2 * k]);
        unsigned u1 = __float_as_uint(f[2 * k + 1]);
        u0 = (u0 + 0x7FFFu + ((u0 >> 16) & 1u)) >> 16;
        u1 = (u1 + 0x7FFFu + ((u1 >> 16) & 1u)) >> 16;
        w[k] = u0 | (u1 << 16);
      }
      ((uint4*)xb)[i] = make_uint4(w[0], w[1], w[2], w[3]);
    }
  }
}

// --- 2. scan of NB bucket counts (1 block) ----------------------------------
__global__ __launch_bounds__(256) void bscan_kernel(
    const int* __restrict__ bhist, int* __restrict__ bbase,
    int* __restrict__ cursor, int NB) {
  __shared__ int partials[256];
  int tid = threadIdx.x;
  int per = (NB + 255) / 256;
  int lo = tid * per, hi = lo + per;
  if (lo > NB) lo = NB;
  if (hi > NB) hi = NB;
  int s = 0;
  for (int i = lo; i < hi; i++) s += bhist[i];
  partials[tid] = s;
  __syncthreads();
  for (int off = 1; off < 256; off <<= 1) {
    int v = partials[tid];
    int a = (tid >= off) ? partials[tid - off] : 0;
    __syncthreads();
    partials[tid] = v + a;
    __syncthreads();
  }
  int run = partials[tid] - s;
  for (int i = lo; i < hi; i++) { bbase[i] = run; cursor[i] = run; run += bhist[i]; }
  if (tid == 255) bbase[NB] = partials[255];
}

// --- 3. bin v3: 8K chunks, LDS staging, dense ~10.5-rec runs ----------------
__global__ __launch_bounds__(512) void bin_kernel(
    const int* __restrict__ src, const int* __restrict__ tgt,
    int* __restrict__ gcursor, unsigned* __restrict__ recs, int E, int NB) {
  __shared__ unsigned rec[CHUNK2];        // 32 KB
  __shared__ unsigned short bkt[CHUNK2];  // 16 KB
  __shared__ int hist[MAXB];              // 4 KB
  __shared__ int gb[MAXB];                // 4 KB
  int tid = threadIdx.x;
  int base = blockIdx.x * CHUNK2;
  int count = E - base; if (count > CHUNK2) count = CHUNK2;

  for (int i = tid; i < NB; i += 512) hist[i] = 0;
  __syncthreads();
  for (int i = tid; i < count; i += 512) {
    int s = src[base + i], t = tgt[base + i];
    int b = t >> 7;
    rec[i] = ((unsigned)s << 7) | (unsigned)(t & 127);
    bkt[i] = (unsigned short)b;
    atomicAdd(&hist[b], 1);
  }
  __syncthreads();
  for (int i = tid; i < NB; i += 512) {
    int c = hist[i];
    gb[i] = c ? atomicAdd(&gcursor[i], c) : 0;
  }
  __syncthreads();
  for (int i = tid; i < NB; i += 512) hist[i] = 0;
  __syncthreads();
  for (int i = tid; i < count; i += 512) {
    int b = (int)bkt[i];
    int idx = atomicAdd(&hist[b], 1);
    recs[gb[b] + idx] = rec[i];
  }
}

// --- 4. fused sort + windowed gather + scale + matmul -----------------------
// One block per bucket, 8 waves. Counting sort by (t_local, src_window).
// Gather pass-outer over 3 source windows (~4.2MB xb each): register acc per
// (node,pass), shfl reduce, one race-free LDS RMW (node rows wave-exclusive).
template <bool USE_BF16>
__global__ __launch_bounds__(512, 4) void sortgather_kernel(
    const float* __restrict__ x, const unsigned* __restrict__ xb,
    const unsigned* __restrict__ recs, const int* __restrict__ bbase,
    const float* __restrict__ norm, const float* __restrict__ W,
    float* __restrict__ out, int N) {
  __shared__ int cnt[BINS];
  __shared__ int pre[BINS];
  __shared__ int nst[BINS + 1];
  __shared__ unsigned sorted[CAP];        // 24 KB (src only)
  __shared__ float accum[BN * ASTRIDE];   // 33.3 KB fp32 partials
  int tid = threadIdx.x;
  int lane = tid & 63;
  int wave = tid >> 6;  // 0..7
  int b = blockIdx.x;
  int n0 = b * BN;
  int nn = N - n0; if (nn > BN) nn = BN;
  int beg = bbase[b], end = bbase[b + 1];
  int m = end - beg;

  float wreg[C];
#pragma unroll
  for (int k = 0; k < C; k++) wreg[k] = W[k * C + lane];

  // init accum with exact fp32 self term
  for (int i = tid; i < nn * C; i += 512) {
    int node = i >> 6, c = i & 63;
    accum[node * ASTRIDE + c] = x[(n0 + node) * C + c];
  }

  // counting sort by (t_local, src window)
  cnt[tid] = 0;
  __syncthreads();
  for (int r = beg + tid; r < end; r += 512) {
    unsigned rc = recs[r];
    int q = (int)(rc >> 22); if (q > 2) q = 2;       // (src>>15) clamped
    atomicAdd(&cnt[(int)(rc & 127u) * 4 + q], 1);
  }
  __syncthreads();
  pre[tid] = cnt[tid];
  __syncthreads();
  for (int off = 1; off < BINS; off <<= 1) {
    int v = pre[tid];
    int a = (tid >= off) ? pre[tid - off] : 0;
    __syncthreads();
    pre[tid] = v + a;
    __syncthreads();
  }
  {
    int excl = pre[tid] - cnt[tid];
    nst[tid] = excl;
    cnt[tid] = excl;  // cursor
  }
  if (tid == 0) nst[BINS] = m;
  __syncthreads();
  bool fits = (m <= CAP);
  if (fits) {
    for (int r = beg + tid; r < end; r += 512) {
      unsigned rc = recs[r];
      int q = (int)(rc >> 22); if (q > 2) q = 2;
      int p = atomicAdd(&cnt[(int)(rc & 127u) * 4 + q], 1);
      sorted[p] = rc >> 7;   // src
    }
  }
  __syncthreads();

  int sub, grp;
  if (USE_BF16) { sub = lane & 7;  grp = lane >> 3; }   // 8 ch-lanes x 8 slots
  else          { sub = lane & 15; grp = lane >> 4; }   // 16 ch-lanes x 4 slots
  const float4* x4 = (const float4*)x;
  const uint4* xb4 = (const uint4*)xb;  // bf16 row = 8 uint4 (128 B)

  if (fits) {
    for (int p = 0; p < NPASS; p++) {
      for (int i = wave; i < nn; i += 8) {
        int gbeg = nst[i * 4 + p], gend = nst[i * 4 + p + 1];
        if (gbeg == gend) continue;
        if (USE_BF16) {
          float acc[8];
#pragma unroll
          for (int j = 0; j < 8; j++) acc[j] = 0.0f;
          for (int e0 = gbeg; e0 < gend; e0 += 16) {
#pragma unroll
            for (int u = 0; u < 2; u++) {
              int e = e0 + 8 * u + grp;
              if (e < gend) {
                int s = (int)sorted[e];
                uint4 v = xb4[s * 8 + sub];
                acc[0] += __uint_as_float(v.x << 16);
                acc[1] += __uint_as_float(v.x & 0xFFFF0000u);
                acc[2] += __uint_as_float(v.y << 16);
                acc[3] += __uint_as_float(v.y & 0xFFFF0000u);
                acc[4] += __uint_as_float(v.z << 16);
                acc[5] += __uint_as_float(v.z & 0xFFFF0000u);
                acc[6] += __uint_as_float(v.w << 16);
                acc[7] += __uint_as_float(v.w & 0xFFFF0000u);
              }
            }
          }
#pragma unroll
          for (int j = 0; j < 8; j++) {
            acc[j] += __shfl_xor(acc[j], 8, 64);
            acc[j] += __shfl_xor(acc[j], 16, 64);
            acc[j] += __shfl_xor(acc[j], 32, 64);
          }
          // race-free RMW: lane (grp,sub) owns channel sub*8+grp
          float v = acc[0];
#pragma unroll
          for (int j = 1; j < 8; j++) v = (grp == j) ? acc[j] : v;
          int c = sub * 8 + grp;
          accum[i * ASTRIDE + c] += v;
        } else {
          float acc[4];
#pragma unroll
          for (int j = 0; j < 4; j++) acc[j] = 0.0f;
          for (int e0 = gbeg; e0 < gend; e0 += 8) {
#pragma unroll
            for (int u = 0; u < 2; u++) {
              int e = e0 + 4 * u + grp;
              if (e < gend) {
                int s = (int)sorted[e];
                float4 v = x4[s * 16 + sub];
                acc[0] += v.x; acc[1] += v.y; acc[2] += v.z; acc[3] += v.w;
              }
            }
          }
#pragma unroll
          for (int j = 0; j < 4; j++) {
            acc[j] += __shfl_xor(acc[j], 16, 64);
            acc[j] += __shfl_xor(acc[j], 32, 64);
          }
          float v = acc[0];
#pragma unroll
          for (int j = 1; j < 4; j++) v = ((grp & 3) == j) ? acc[j] : v;
          int c = sub * 4 + (grp & 3);
          accum[i * ASTRIDE + c] += v;
        }
      }
    }
  } else {  // overflow fallback (statistically unreachable): filtered scan
    for (int i = wave; i < nn; i += 8) {
      if (USE_BF16) {
        float acc[8];
#pragma unroll
        for (int j = 0; j < 8; j++) acc[j] = 0.0f;
        for (int r0 = beg; r0 < end; r0 += 8) {
          int e = r0 + grp;
          if (e < end) {
            unsigned rc = recs[e];
            if ((int)(rc & 127u) == i) {
              int s = (int)(rc >> 7);
              uint4 v = xb4[s * 8 + sub];
              acc[0] += __uint_as_float(v.x << 16);
              acc[1] += __uint_as_float(v.x & 0xFFFF0000u);
              acc[2] += __uint_as_float(v.y << 16);
              acc[3] += __uint_as_float(v.y & 0xFFFF0000u);
              acc[4] += __uint_as_float(v.z << 16);
              acc[5] += __uint_as_float(v.z & 0xFFFF0000u);
              acc[6] += __uint_as_float(v.w << 16);
              acc[7] += __uint_as_float(v.w & 0xFFFF0000u);
            }
          }
        }
#pragma unroll
        for (int j = 0; j < 8; j++) {
          acc[j] += __shfl_xor(acc[j], 8, 64);
          acc[j] += __shfl_xor(acc[j], 16, 64);
          acc[j] += __shfl_xor(acc[j], 32, 64);
        }
        float v = acc[0];
#pragma unroll
        for (int j = 1; j < 8; j++) v = (grp == j) ? acc[j] : v;
        accum[i * ASTRIDE + sub * 8 + grp] += v;
      } else {
        float acc[4];
#pragma unroll
        for (int j = 0; j < 4; j++) acc[j] = 0.0f;
        for (int r0 = beg; r0 < end; r0 += 4) {
          int e = r0 + grp;
          if (e < end) {
            unsigned rc = recs[e];
            if ((int)(rc & 127u) == i) {
              int s = (int)(rc >> 7);
              float4 v = x4[s * 16 + sub];
              acc[0] += v.x; acc[1] += v.y; acc[2] += v.z; acc[3] += v.w;
            }
          }
        }
#pragma unroll
        for (int j = 0; j < 4; j++) {
          acc[j] += __shfl_xor(acc[j], 16, 64);
          acc[j] += __shfl_xor(acc[j], 32, 64);
        }
        float v = acc[0];
#pragma unroll
        for (int j = 1; j < 4; j++) v = ((grp & 3) == j) ? acc[j] : v;
        accum[i * ASTRIDE + sub * 4 + (grp & 3)] += v;
      }
    }
  }
  __syncthreads();

  // epilogue: out[n][lane] = norm[n] * sum_c accum[n][c] * W[c][lane]
  for (int i = wave; i < nn; i += 8) {
    int n = n0 + i;
    float a = accum[i * ASTRIDE + lane];   // lane holds channel `lane`
    float o = 0.0f;
#pragma unroll
    for (int c = 0; c < C; c++)
      o = fmaf(__shfl(a, c, 64), wreg[c], o);
    out[n * C + lane] = o * norm[n];
  }
}

extern "C" void kernel_launch(void* const* d_in, const int* in_sizes, int n_in,
                              void* d_out, int out_size, void* d_ws, size_t ws_size,
                              hipStream_t stream) {
  const float* x       = (const float*)d_in[0];
  const int*   sources = (const int*)d_in[1];
  const int*   targets = (const int*)d_in[2];
  const float* norm    = (const float*)d_in[3];
  const float* weight  = (const float*)d_in[4];
  float* out = (float*)d_out;

  int N = in_sizes[0] / C;     // 100000
  int E = in_sizes[1];         // 4000000
  int NB = (N + BN - 1) / BN;  // 782

  // ws (bf16): xb 12.8MB | bhist[NB] | bbase[NB+1] | cursor[NB] | recs[E] -> 28.8MB
  size_t xb_words = (size_t)N * C / 2;  // bf16 vals packed in unsigned words
  size_t meta_words = (size_t)3 * NB + 1 + (size_t)E;
  bool use_bf16 = ws_size >= (xb_words + meta_words) * 4;

  unsigned* xb; int* bhist;
  if (use_bf16) {
    xb = (unsigned*)d_ws;                 // 16B-aligned block first
    bhist = (int*)d_ws + xb_words;
  } else {
    xb = nullptr;
    bhist = (int*)d_ws;
  }
  int* bbase  = bhist + NB;
  int* cursor = bbase + (NB + 1);
  unsigned* recs = (unsigned*)(cursor + NB);

  hipMemsetAsync(bhist, 0, (size_t)NB * sizeof(int), stream);

  int hb = (E + CHUNK2 - 1) / CHUNK2;  // 489
  int total8 = N * C / 8;              // 800000
  int cvtBlocks = use_bf16 ? (total8 + 511) / 512 : 0;
  prep_kernel<<<hb + cvtBlocks, 512, 0, stream>>>(x, xb, targets, bhist, E, NB, hb, total8);
  bscan_kernel<<<1, 256, 0, stream>>>(bhist, bbase, cursor, NB);
  bin_kernel<<<hb, 512, 0, stream>>>(sources, targets, cursor, recs, E, NB);
  if (use_bf16) {
    sortgather_kernel<true><<<NB, 512, 0, stream>>>(x, xb, recs, bbase, norm, weight, out, N);
  } else {
    sortgather_kernel<false><<<NB, 512, 0, stream>>>(x, xb, recs, bbase, norm, weight, out, N);
  }
}

// Round 4
// 303.180 us; speedup vs baseline: 6.2320x; 1.2954x over previous
//
#include <hip/hip_runtime.h>

// Conv: out = (norm * (x + segment_sum(x[sources], targets))) @ W
// N = 100000, E = 4000000, C = 64, fp32.
// Pipeline: prep (fused x->bf16 cvt + bucket hist) -> tiny scan -> bin v3
// (8K-chunk LDS-staged dense-run bucket sort) -> sortgather.
// NOTE: fp8 gather tried in R9 -> absmax 0.875 > 0.65 threshold. bf16 is the
// floor precision. Self term exact fp32.
// R10: 512 threads -> NEUTRAL (170us): throughput insensitive to wave count.
// R11: LDS fp32 atomic accumulation -> 1742us DISASTER. Lesson: per-edge-
// channel LDS accumulation is fatal; register accumulation mandatory.
// R12: (t_local, src_window) sort + 3-pass window-major gather: FETCH 200->116
// MB (L2 hit 69->86%) BUT dur 170->255us: 4.4-edge segments each followed by a
// serial 24-shfl reduce + LDS RMW -> per-wave MLP collapsed. Lesson: locality
// restructure must preserve uninterrupted load streams.
// R13: group-per-node gather. 8-lane group owns a node (lane = one uint4 = 8
// channels); 2 nodes/group (g, g+64) with acc in REGISTERS across all 3
// windows. Zero shfl, zero LDS RMW during gather; loads stream continuously
// (unroll 2). Window-major order kept => locality of R12 + streaming of R1.
// accum LDS reuses sorted[] union space after a barrier.

constexpr int C = 64;
constexpr int BN = 128;       // nodes per bucket
constexpr int CHUNK2 = 8192;  // edges per hist/bin block (512 threads)
constexpr int MAXB = 1024;    // LDS bucket arrays capacity (NB = 782)
constexpr int CAP = 8192;     // LDS sort staging (bucket avg 5120, max ~5500)
constexpr int NPASS = 3;      // source windows (src>>15 clamped to 0..2)
constexpr int BINS = BN * 4;  // (t_local, window) bins; slot 3 unused
constexpr int ASTRIDE = 65;   // accum row stride (bank rotation; 65 % 32 == 1)
constexpr int UNI = BN * ASTRIDE;  // 8320 words >= CAP: union{sorted, accum}

// --- 1. fused: x -> bf16 (RNE)  +  bucket histogram -------------------------
__global__ __launch_bounds__(512) void prep_kernel(
    const float* __restrict__ x, unsigned* __restrict__ xb,
    const int* __restrict__ tgt, int* __restrict__ bhist,
    int E, int NB, int histBlocks, int total8) {
  __shared__ int h[MAXB];
  if ((int)blockIdx.x < histBlocks) {
    for (int i = threadIdx.x; i < NB; i += 512) h[i] = 0;
    __syncthreads();
    int base = blockIdx.x * CHUNK2;
    int end = base + CHUNK2; if (end > E) end = E;
    for (int i = base + threadIdx.x; i < end; i += 512)
      atomicAdd(&h[tgt[i] >> 7], 1);
    __syncthreads();
    for (int i = threadIdx.x; i < NB; i += 512)
      if (h[i]) atomicAdd(&bhist[i], h[i]);
  } else {
    int i = (blockIdx.x - histBlocks) * 512 + threadIdx.x;  // 8 floats each
    if (i < total8) {
      const float4* x4 = (const float4*)x;
      float4 a = x4[i * 2], bq = x4[i * 2 + 1];
      float f[8] = {a.x, a.y, a.z, a.w, bq.x, bq.y, bq.z, bq.w};
      unsigned w[4];
#pragma unroll
      for (int k = 0; k < 4; k++) {
        unsigned u0 = __float_as_uint(f[2 * k]);
        unsigned u1 = __float_as_uint(f[2 * k + 1]);
        u0 = (u0 + 0x7FFFu + ((u0 >> 16) & 1u)) >> 16;
        u1 = (u1 + 0x7FFFu + ((u1 >> 16) & 1u)) >> 16;
        w[k] = u0 | (u1 << 16);
      }
      ((uint4*)xb)[i] = make_uint4(w[0], w[1], w[2], w[3]);
    }
  }
}

// --- 2. scan of NB bucket counts (1 block) ----------------------------------
__global__ __launch_bounds__(256) void bscan_kernel(
    const int* __restrict__ bhist, int* __restrict__ bbase,
    int* __restrict__ cursor, int NB) {
  __shared__ int partials[256];
  int tid = threadIdx.x;
  int per = (NB + 255) / 256;
  int lo = tid * per, hi = lo + per;
  if (lo > NB) lo = NB;
  if (hi > NB) hi = NB;
  int s = 0;
  for (int i = lo; i < hi; i++) s += bhist[i];
  partials[tid] = s;
  __syncthreads();
  for (int off = 1; off < 256; off <<= 1) {
    int v = partials[tid];
    int a = (tid >= off) ? partials[tid - off] : 0;
    __syncthreads();
    partials[tid] = v + a;
    __syncthreads();
  }
  int run = partials[tid] - s;
  for (int i = lo; i < hi; i++) { bbase[i] = run; cursor[i] = run; run += bhist[i]; }
  if (tid == 255) bbase[NB] = partials[255];
}

// --- 3. bin v3: 8K chunks, LDS staging, dense ~10.5-rec runs ----------------
__global__ __launch_bounds__(512) void bin_kernel(
    const int* __restrict__ src, const int* __restrict__ tgt,
    int* __restrict__ gcursor, unsigned* __restrict__ recs, int E, int NB) {
  __shared__ unsigned rec[CHUNK2];        // 32 KB
  __shared__ unsigned short bkt[CHUNK2];  // 16 KB
  __shared__ int hist[MAXB];              // 4 KB
  __shared__ int gb[MAXB];                // 4 KB
  int tid = threadIdx.x;
  int base = blockIdx.x * CHUNK2;
  int count = E - base; if (count > CHUNK2) count = CHUNK2;

  for (int i = tid; i < NB; i += 512) hist[i] = 0;
  __syncthreads();
  for (int i = tid; i < count; i += 512) {
    int s = src[base + i], t = tgt[base + i];
    int b = t >> 7;
    rec[i] = ((unsigned)s << 7) | (unsigned)(t & 127);
    bkt[i] = (unsigned short)b;
    atomicAdd(&hist[b], 1);
  }
  __syncthreads();
  for (int i = tid; i < NB; i += 512) {
    int c = hist[i];
    gb[i] = c ? atomicAdd(&gcursor[i], c) : 0;
  }
  __syncthreads();
  for (int i = tid; i < NB; i += 512) hist[i] = 0;
  __syncthreads();
  for (int i = tid; i < count; i += 512) {
    int b = (int)bkt[i];
    int idx = atomicAdd(&hist[b], 1);
    recs[gb[b] + idx] = rec[i];
  }
}

__device__ __forceinline__ void acc8_bf16(float (&a)[8], uint4 v) {
  a[0] += __uint_as_float(v.x << 16);
  a[1] += __uint_as_float(v.x & 0xFFFF0000u);
  a[2] += __uint_as_float(v.y << 16);
  a[3] += __uint_as_float(v.y & 0xFFFF0000u);
  a[4] += __uint_as_float(v.z << 16);
  a[5] += __uint_as_float(v.z & 0xFFFF0000u);
  a[6] += __uint_as_float(v.w << 16);
  a[7] += __uint_as_float(v.w & 0xFFFF0000u);
}

__device__ __forceinline__ void acc8_f32(float (&a)[8], float4 u, float4 v) {
  a[0] += u.x; a[1] += u.y; a[2] += u.z; a[3] += u.w;
  a[4] += v.x; a[5] += v.y; a[6] += v.z; a[7] += v.w;
}

// --- 4. fused sort + windowed group-per-node gather + scale + matmul --------
// One block per bucket, 8 waves. Counting sort by (t_local, src_window).
// Gather: 8-lane group owns nodes g and g+64; lane = 8 channels; acc in
// registers across all 3 window passes (no shfl, no LDS RMW). Then acc ->
// LDS accum (union over sorted) -> shfl-matmul epilogue.
template <bool USE_BF16>
__global__ __launch_bounds__(512, 2) void sortgather_kernel(
    const float* __restrict__ x, const unsigned* __restrict__ xb,
    const unsigned* __restrict__ recs, const int* __restrict__ bbase,
    const float* __restrict__ norm, const float* __restrict__ W,
    float* __restrict__ out, int N) {
  __shared__ int cnt[BINS];
  __shared__ int pre[BINS];
  __shared__ int nst[BINS + 1];
  __shared__ float uni[UNI];   // 33.3 KB union: sorted[CAP] | accum[BN*65]
  unsigned* sorted = (unsigned*)uni;
  float* accum = uni;
  int tid = threadIdx.x;
  int lane = tid & 63;
  int wave = tid >> 6;  // 0..7
  int b = blockIdx.x;
  int n0 = b * BN;
  int nn = N - n0; if (nn > BN) nn = BN;
  int beg = bbase[b], end = bbase[b + 1];
  int m = end - beg;

  float wreg[C];
#pragma unroll
  for (int k = 0; k < C; k++) wreg[k] = W[k * C + lane];

  // counting sort by (t_local, src window)
  cnt[tid] = 0;
  __syncthreads();
  for (int r = beg + tid; r < end; r += 512) {
    unsigned rc = recs[r];
    int q = (int)(rc >> 22); if (q > 2) q = 2;       // (src>>15) clamped
    atomicAdd(&cnt[(int)(rc & 127u) * 4 + q], 1);
  }
  __syncthreads();
  pre[tid] = cnt[tid];
  __syncthreads();
  for (int off = 1; off < BINS; off <<= 1) {
    int v = pre[tid];
    int a = (tid >= off) ? pre[tid - off] : 0;
    __syncthreads();
    pre[tid] = v + a;
    __syncthreads();
  }
  {
    int excl = pre[tid] - cnt[tid];
    nst[tid] = excl;
    cnt[tid] = excl;  // cursor
  }
  if (tid == 0) nst[BINS] = m;
  __syncthreads();
  bool fits = (m <= CAP);
  if (fits) {
    for (int r = beg + tid; r < end; r += 512) {
      unsigned rc = recs[r];
      int q = (int)(rc >> 22); if (q > 2) q = 2;
      int p = atomicAdd(&cnt[(int)(rc & 127u) * 4 + q], 1);
      sorted[p] = rc >> 7;   // src
    }
  }
  __syncthreads();

  // ---- group-per-node gather, acc in registers ----
  int l7 = tid & 7;
  int g  = tid >> 3;          // 0..63 (group id across whole block)
  int k0 = g, k1 = g + 64;
  bool has0 = k0 < nn, has1 = k1 < nn;
  const float4* x4 = (const float4*)x;
  const uint4* xb4 = (const uint4*)xb;  // bf16 row = 8 uint4 (128 B)

  float a0[8], a1[8];
  // exact fp32 self term into registers
  if (has0) {
    float4 u = x4[(n0 + k0) * 16 + l7 * 2], v = x4[(n0 + k0) * 16 + l7 * 2 + 1];
    a0[0] = u.x; a0[1] = u.y; a0[2] = u.z; a0[3] = u.w;
    a0[4] = v.x; a0[5] = v.y; a0[6] = v.z; a0[7] = v.w;
  } else {
#pragma unroll
    for (int j = 0; j < 8; j++) a0[j] = 0.0f;
  }
  if (has1) {
    float4 u = x4[(n0 + k1) * 16 + l7 * 2], v = x4[(n0 + k1) * 16 + l7 * 2 + 1];
    a1[0] = u.x; a1[1] = u.y; a1[2] = u.z; a1[3] = u.w;
    a1[4] = v.x; a1[5] = v.y; a1[6] = v.z; a1[7] = v.w;
  } else {
#pragma unroll
    for (int j = 0; j < 8; j++) a1[j] = 0.0f;
  }

  if (fits) {
#pragma unroll
    for (int p = 0; p < NPASS; p++) {
      if (has0) {
        int e = nst[k0 * 4 + p], ge = nst[k0 * 4 + p + 1];
        for (; e + 1 < ge; e += 2) {
          int s0 = (int)sorted[e], s1 = (int)sorted[e + 1];
          if (USE_BF16) {
            uint4 v0 = xb4[s0 * 8 + l7];
            uint4 v1 = xb4[s1 * 8 + l7];
            acc8_bf16(a0, v0); acc8_bf16(a0, v1);
          } else {
            float4 u0 = x4[s0 * 16 + l7 * 2], w0 = x4[s0 * 16 + l7 * 2 + 1];
            float4 u1 = x4[s1 * 16 + l7 * 2], w1 = x4[s1 * 16 + l7 * 2 + 1];
            acc8_f32(a0, u0, w0); acc8_f32(a0, u1, w1);
          }
        }
        if (e < ge) {
          int s = (int)sorted[e];
          if (USE_BF16) { uint4 v = xb4[s * 8 + l7]; acc8_bf16(a0, v); }
          else { acc8_f32(a0, x4[s * 16 + l7 * 2], x4[s * 16 + l7 * 2 + 1]); }
        }
      }
      if (has1) {
        int e = nst[k1 * 4 + p], ge = nst[k1 * 4 + p + 1];
        for (; e + 1 < ge; e += 2) {
          int s0 = (int)sorted[e], s1 = (int)sorted[e + 1];
          if (USE_BF16) {
            uint4 v0 = xb4[s0 * 8 + l7];
            uint4 v1 = xb4[s1 * 8 + l7];
            acc8_bf16(a1, v0); acc8_bf16(a1, v1);
          } else {
            float4 u0 = x4[s0 * 16 + l7 * 2], w0 = x4[s0 * 16 + l7 * 2 + 1];
            float4 u1 = x4[s1 * 16 + l7 * 2], w1 = x4[s1 * 16 + l7 * 2 + 1];
            acc8_f32(a1, u0, w0); acc8_f32(a1, u1, w1);
          }
        }
        if (e < ge) {
          int s = (int)sorted[e];
          if (USE_BF16) { uint4 v = xb4[s * 8 + l7]; acc8_bf16(a1, v); }
          else { acc8_f32(a1, x4[s * 16 + l7 * 2], x4[s * 16 + l7 * 2 + 1]); }
        }
      }
    }
  } else {  // overflow fallback (statistically unreachable): filtered scan
    for (int r = beg; r < end; r++) {
      unsigned rc = recs[r];
      int tl = (int)(rc & 127u);
      if (tl == k0 || tl == k1) {
        int s = (int)(rc >> 7);
        if (USE_BF16) {
          uint4 v = xb4[s * 8 + l7];
          if (tl == k0) acc8_bf16(a0, v); else acc8_bf16(a1, v);
        } else {
          float4 u = x4[s * 16 + l7 * 2], w = x4[s * 16 + l7 * 2 + 1];
          if (tl == k0) acc8_f32(a0, u, w); else acc8_f32(a1, u, w);
        }
      }
    }
  }
  __syncthreads();  // all groups done reading sorted[] before overwrite

  // dump register acc into accum (union space)
  if (has0) {
#pragma unroll
    for (int j = 0; j < 8; j++) accum[k0 * ASTRIDE + 8 * l7 + j] = a0[j];
  }
  if (has1) {
#pragma unroll
    for (int j = 0; j < 8; j++) accum[k1 * ASTRIDE + 8 * l7 + j] = a1[j];
  }
  __syncthreads();

  // epilogue: out[n][lane] = norm[n] * sum_c accum[n][c] * W[c][lane]
  for (int i = wave; i < nn; i += 8) {
    int n = n0 + i;
    float a = accum[i * ASTRIDE + lane];   // lane holds channel `lane`
    float o = 0.0f;
#pragma unroll
    for (int c = 0; c < C; c++)
      o = fmaf(__shfl(a, c, 64), wreg[c], o);
    out[n * C + lane] = o * norm[n];
  }
}

extern "C" void kernel_launch(void* const* d_in, const int* in_sizes, int n_in,
                              void* d_out, int out_size, void* d_ws, size_t ws_size,
                              hipStream_t stream) {
  const float* x       = (const float*)d_in[0];
  const int*   sources = (const int*)d_in[1];
  const int*   targets = (const int*)d_in[2];
  const float* norm    = (const float*)d_in[3];
  const float* weight  = (const float*)d_in[4];
  float* out = (float*)d_out;

  int N = in_sizes[0] / C;     // 100000
  int E = in_sizes[1];         // 4000000
  int NB = (N + BN - 1) / BN;  // 782

  // ws (bf16): xb 12.8MB | bhist[NB] | bbase[NB+1] | cursor[NB] | recs[E] -> 28.8MB
  size_t xb_words = (size_t)N * C / 2;  // bf16 vals packed in unsigned words
  size_t meta_words = (size_t)3 * NB + 1 + (size_t)E;
  bool use_bf16 = ws_size >= (xb_words + meta_words) * 4;

  unsigned* xb; int* bhist;
  if (use_bf16) {
    xb = (unsigned*)d_ws;                 // 16B-aligned block first
    bhist = (int*)d_ws + xb_words;
  } else {
    xb = nullptr;
    bhist = (int*)d_ws;
  }
  int* bbase  = bhist + NB;
  int* cursor = bbase + (NB + 1);
  unsigned* recs = (unsigned*)(cursor + NB);

  hipMemsetAsync(bhist, 0, (size_t)NB * sizeof(int), stream);

  int hb = (E + CHUNK2 - 1) / CHUNK2;  // 489
  int total8 = N * C / 8;              // 800000
  int cvtBlocks = use_bf16 ? (total8 + 511) / 512 : 0;
  prep_kernel<<<hb + cvtBlocks, 512, 0, stream>>>(x, xb, targets, bhist, E, NB, hb, total8);
  bscan_kernel<<<1, 256, 0, stream>>>(bhist, bbase, cursor, NB);
  bin_kernel<<<hb, 512, 0, stream>>>(sources, targets, cursor, recs, E, NB);
  if (use_bf16) {
    sortgather_kernel<true><<<NB, 512, 0, stream>>>(x, xb, recs, bbase, norm, weight, out, N);
  } else {
    sortgather_kernel<false><<<NB, 512, 0, stream>>>(x, xb, recs, bbase, norm, weight, out, N);
  }
}

// Round 5
// 280.470 us; speedup vs baseline: 6.7366x; 1.0810x over previous
//
#include <hip/hip_runtime.h>

// Conv: out = (norm * (x + segment_sum(x[sources], targets))) @ W
// N = 100000, E = 4000000, C = 64, fp32.
// Pipeline (R14): init (slab cursors) -> binfused (slab bucket sort + bf16
// cvt blocks in one grid) -> sortgather (per-bucket counting sort by
// (t_local, src_window) + group-per-node register gather + shfl matmul).
// NOTE: fp8 gather tried in R9 -> absmax 0.875 > 0.65 threshold. bf16 is the
// floor precision. Self term exact fp32.
// R10: 512 threads -> NEUTRAL (170us): throughput insensitive to wave count.
// R11: LDS fp32 atomic accumulation -> 1742us DISASTER. Lesson: per-edge-
// channel LDS accumulation is fatal; register accumulation mandatory.
// R12: (t_local,src_window) sort + 3-pass gather: FETCH 200->116MB but
// dur 255us (per-segment shfl reduce killed MLP). Lesson: locality
// restructure must preserve uninterrupted load streams.
// R13: group-per-node register gather (8-lane group owns node; acc in regs
// across windows, zero shfl during gather): sortgather 158us, FETCH 122MB.
// Total 303us => front-end (prep+bscan+bin) = 145us for ~102MB traffic (7x
// roofline: targets read twice for exact hist+scan).
// R14: fixed per-bucket slabs (slot=8192, +43 sigma over mean 5115) remove
// hist+scan+memset entirely; bin reserves runs from slab cursors; global
// tail region keeps overflow correct. Phase-1 int4-vectorized. cvt fused
// into same grid. sortgather hot path untouched.

constexpr int C = 64;
constexpr int BN = 128;        // nodes per bucket
constexpr int CHUNK2 = 8192;   // edges per bin block (512 threads)
constexpr int MAXB = 1024;     // LDS bucket arrays capacity (NB = 782)
constexpr int NPASS = 3;       // source windows (src>>15 clamped to 0..2)
constexpr int BINS = BN * 4;   // (t_local, window) bins; slot 3 unused
constexpr int ASTRIDE = 65;    // accum row stride (bank rotation)
constexpr int UNI = BN * ASTRIDE;  // 8320 words >= slot: union{sorted, accum}
constexpr int TAILCAP = 65536; // overflow records (normally 0 used)

// --- 0. slab cursor init ----------------------------------------------------
__global__ __launch_bounds__(256) void init_kernel(
    int* __restrict__ cursor, int* __restrict__ tailcnt, int NB, int slot) {
  int i = blockIdx.x * 256 + threadIdx.x;
  if (i < NB) cursor[i] = i * slot;
  if (i == NB) *tailcnt = 0;
}

// --- 1. fused slab bucket-sort + x->bf16 cvt --------------------------------
__global__ __launch_bounds__(512) void binfused_kernel(
    const int* __restrict__ src, const int* __restrict__ tgt,
    int* __restrict__ gcursor, int* __restrict__ tailcnt,
    unsigned* __restrict__ tailrec, unsigned* __restrict__ recs,
    const float* __restrict__ x, unsigned* __restrict__ xb,
    int E, int NB, int slot, int binBlocks, int total8) {
  if ((int)blockIdx.x >= binBlocks) {  // ---- bf16 convert blocks ----
    int i = (blockIdx.x - binBlocks) * 512 + threadIdx.x;  // 8 floats each
    if (i < total8) {
      const float4* x4 = (const float4*)x;
      float4 a = x4[i * 2], bq = x4[i * 2 + 1];
      float f[8] = {a.x, a.y, a.z, a.w, bq.x, bq.y, bq.z, bq.w};
      unsigned w[4];
#pragma unroll
      for (int k = 0; k < 4; k++) {
        unsigned u0 = __float_as_uint(f[2 * k]);
        unsigned u1 = __float_as_uint(f[2 * k + 1]);
        u0 = (u0 + 0x7FFFu + ((u0 >> 16) & 1u)) >> 16;
        u1 = (u1 + 0x7FFFu + ((u1 >> 16) & 1u)) >> 16;
        w[k] = u0 | (u1 << 16);
      }
      ((uint4*)xb)[i] = make_uint4(w[0], w[1], w[2], w[3]);
    }
    return;
  }
  // ---- bin blocks: LDS-staged dense-run slab scatter ----
  __shared__ unsigned rec[CHUNK2];        // 32 KB
  __shared__ unsigned short bkt[CHUNK2];  // 16 KB
  __shared__ int hist[MAXB];              // 4 KB
  __shared__ int gb[MAXB];                // 4 KB
  int tid = threadIdx.x;
  int base = blockIdx.x * CHUNK2;
  int count = E - base; if (count > CHUNK2) count = CHUNK2;

  for (int i = tid; i < NB; i += 512) hist[i] = 0;
  __syncthreads();
  int nv = count >> 2;
  const int4* s4 = (const int4*)(src + base);
  const int4* t4 = (const int4*)(tgt + base);
  for (int i = tid; i < nv; i += 512) {
    int4 s = s4[i], t = t4[i];
    unsigned r0 = ((unsigned)s.x << 7) | (unsigned)(t.x & 127);
    unsigned r1 = ((unsigned)s.y << 7) | (unsigned)(t.y & 127);
    unsigned r2 = ((unsigned)s.z << 7) | (unsigned)(t.z & 127);
    unsigned r3 = ((unsigned)s.w << 7) | (unsigned)(t.w & 127);
    ((uint4*)rec)[i] = make_uint4(r0, r1, r2, r3);
    int b0 = t.x >> 7, b1 = t.y >> 7, b2 = t.z >> 7, b3 = t.w >> 7;
    ((ushort4*)bkt)[i] = make_ushort4(
        (unsigned short)b0, (unsigned short)b1,
        (unsigned short)b2, (unsigned short)b3);
    atomicAdd(&hist[b0], 1); atomicAdd(&hist[b1], 1);
    atomicAdd(&hist[b2], 1); atomicAdd(&hist[b3], 1);
  }
  for (int i = (nv << 2) + tid; i < count; i += 512) {
    int s = src[base + i], t = tgt[base + i];
    int b = t >> 7;
    rec[i] = ((unsigned)s << 7) | (unsigned)(t & 127);
    bkt[i] = (unsigned short)b;
    atomicAdd(&hist[b], 1);
  }
  __syncthreads();
  for (int i = tid; i < NB; i += 512) {
    int c = hist[i];
    gb[i] = c ? atomicAdd(&gcursor[i], c) : 0;
  }
  __syncthreads();
  for (int i = tid; i < NB; i += 512) hist[i] = 0;
  __syncthreads();
  for (int i = tid; i < count; i += 512) {
    int b = (int)bkt[i];
    int idx = atomicAdd(&hist[b], 1);
    int dest = gb[b] + idx;
    if (dest < (b + 1) * slot) {
      recs[dest] = rec[i];
    } else {  // slab overflow (statistically unreachable): spill to tail
      int tp = atomicAdd(tailcnt, 1);
      if (tp < TAILCAP) {
        tailrec[2 * tp] = rec[i];
        tailrec[2 * tp + 1] = (unsigned)b;
      }
    }
  }
}

__device__ __forceinline__ void acc8_bf16(float (&a)[8], uint4 v) {
  a[0] += __uint_as_float(v.x << 16);
  a[1] += __uint_as_float(v.x & 0xFFFF0000u);
  a[2] += __uint_as_float(v.y << 16);
  a[3] += __uint_as_float(v.y & 0xFFFF0000u);
  a[4] += __uint_as_float(v.z << 16);
  a[5] += __uint_as_float(v.z & 0xFFFF0000u);
  a[6] += __uint_as_float(v.w << 16);
  a[7] += __uint_as_float(v.w & 0xFFFF0000u);
}

__device__ __forceinline__ void acc8_f32(float (&a)[8], float4 u, float4 v) {
  a[0] += u.x; a[1] += u.y; a[2] += u.z; a[3] += u.w;
  a[4] += v.x; a[5] += v.y; a[6] += v.z; a[7] += v.w;
}

// --- 2. fused sort + windowed group-per-node gather + scale + matmul --------
// One block per bucket, 8 waves. Counting sort by (t_local, src_window).
// Gather: 8-lane group owns nodes g and g+64; lane = 8 channels; acc in
// registers across all 3 window passes (no shfl, no LDS RMW). Then acc ->
// LDS accum (union over sorted) -> shfl-matmul epilogue.
template <bool USE_BF16>
__global__ __launch_bounds__(512, 2) void sortgather_kernel(
    const float* __restrict__ x, const unsigned* __restrict__ xb,
    const unsigned* __restrict__ recs, const int* __restrict__ cursor,
    const int* __restrict__ tailcnt, const unsigned* __restrict__ tailrec,
    const float* __restrict__ norm, const float* __restrict__ W,
    float* __restrict__ out, int N, int slot) {
  __shared__ int cnt[BINS];
  __shared__ int pre[BINS];
  __shared__ int nst[BINS + 1];
  __shared__ float uni[UNI];   // 33.3 KB union: sorted[slot] | accum[BN*65]
  unsigned* sorted = (unsigned*)uni;
  float* accum = uni;
  int tid = threadIdx.x;
  int lane = tid & 63;
  int wave = tid >> 6;  // 0..7
  int b = blockIdx.x;
  int n0 = b * BN;
  int nn = N - n0; if (nn > BN) nn = BN;
  int beg = b * slot;
  int m = cursor[b] - beg; if (m > slot) m = slot;
  int end = beg + m;

  float wreg[C];
#pragma unroll
  for (int k = 0; k < C; k++) wreg[k] = W[k * C + lane];

  // counting sort by (t_local, src window)
  cnt[tid] = 0;
  __syncthreads();
  for (int r = beg + tid; r < end; r += 512) {
    unsigned rc = recs[r];
    int q = (int)(rc >> 22); if (q > 2) q = 2;       // (src>>15) clamped
    atomicAdd(&cnt[(int)(rc & 127u) * 4 + q], 1);
  }
  __syncthreads();
  pre[tid] = cnt[tid];
  __syncthreads();
  for (int off = 1; off < BINS; off <<= 1) {
    int v = pre[tid];
    int a = (tid >= off) ? pre[tid - off] : 0;
    __syncthreads();
    pre[tid] = v + a;
    __syncthreads();
  }
  {
    int excl = pre[tid] - cnt[tid];
    nst[tid] = excl;
    cnt[tid] = excl;  // cursor
  }
  if (tid == 0) nst[BINS] = m;
  __syncthreads();
  for (int r = beg + tid; r < end; r += 512) {
    unsigned rc = recs[r];
    int q = (int)(rc >> 22); if (q > 2) q = 2;
    int p = atomicAdd(&cnt[(int)(rc & 127u) * 4 + q], 1);
    sorted[p] = rc >> 7;   // src
  }
  __syncthreads();

  // ---- group-per-node gather, acc in registers ----
  int l7 = tid & 7;
  int g  = tid >> 3;          // 0..63 (group id across whole block)
  int k0 = g, k1 = g + 64;
  bool has0 = k0 < nn, has1 = k1 < nn;
  const float4* x4 = (const float4*)x;
  const uint4* xb4 = (const uint4*)xb;  // bf16 row = 8 uint4 (128 B)

  float a0[8], a1[8];
  // exact fp32 self term into registers
  if (has0) {
    float4 u = x4[(n0 + k0) * 16 + l7 * 2], v = x4[(n0 + k0) * 16 + l7 * 2 + 1];
    a0[0] = u.x; a0[1] = u.y; a0[2] = u.z; a0[3] = u.w;
    a0[4] = v.x; a0[5] = v.y; a0[6] = v.z; a0[7] = v.w;
  } else {
#pragma unroll
    for (int j = 0; j < 8; j++) a0[j] = 0.0f;
  }
  if (has1) {
    float4 u = x4[(n0 + k1) * 16 + l7 * 2], v = x4[(n0 + k1) * 16 + l7 * 2 + 1];
    a1[0] = u.x; a1[1] = u.y; a1[2] = u.z; a1[3] = u.w;
    a1[4] = v.x; a1[5] = v.y; a1[6] = v.z; a1[7] = v.w;
  } else {
#pragma unroll
    for (int j = 0; j < 8; j++) a1[j] = 0.0f;
  }

#pragma unroll
  for (int p = 0; p < NPASS; p++) {
    if (has0) {
      int e = nst[k0 * 4 + p], ge = nst[k0 * 4 + p + 1];
      for (; e + 1 < ge; e += 2) {
        int s0 = (int)sorted[e], s1 = (int)sorted[e + 1];
        if (USE_BF16) {
          uint4 v0 = xb4[s0 * 8 + l7];
          uint4 v1 = xb4[s1 * 8 + l7];
          acc8_bf16(a0, v0); acc8_bf16(a0, v1);
        } else {
          float4 u0 = x4[s0 * 16 + l7 * 2], w0 = x4[s0 * 16 + l7 * 2 + 1];
          float4 u1 = x4[s1 * 16 + l7 * 2], w1 = x4[s1 * 16 + l7 * 2 + 1];
          acc8_f32(a0, u0, w0); acc8_f32(a0, u1, w1);
        }
      }
      if (e < ge) {
        int s = (int)sorted[e];
        if (USE_BF16) { uint4 v = xb4[s * 8 + l7]; acc8_bf16(a0, v); }
        else { acc8_f32(a0, x4[s * 16 + l7 * 2], x4[s * 16 + l7 * 2 + 1]); }
      }
    }
    if (has1) {
      int e = nst[k1 * 4 + p], ge = nst[k1 * 4 + p + 1];
      for (; e + 1 < ge; e += 2) {
        int s0 = (int)sorted[e], s1 = (int)sorted[e + 1];
        if (USE_BF16) {
          uint4 v0 = xb4[s0 * 8 + l7];
          uint4 v1 = xb4[s1 * 8 + l7];
          acc8_bf16(a1, v0); acc8_bf16(a1, v1);
        } else {
          float4 u0 = x4[s0 * 16 + l7 * 2], w0 = x4[s0 * 16 + l7 * 2 + 1];
          float4 u1 = x4[s1 * 16 + l7 * 2], w1 = x4[s1 * 16 + l7 * 2 + 1];
          acc8_f32(a1, u0, w0); acc8_f32(a1, u1, w1);
        }
      }
      if (e < ge) {
        int s = (int)sorted[e];
        if (USE_BF16) { uint4 v = xb4[s * 8 + l7]; acc8_bf16(a1, v); }
        else { acc8_f32(a1, x4[s * 16 + l7 * 2], x4[s * 16 + l7 * 2 + 1]); }
      }
    }
  }

  // tail (slab-overflow) records: normally zero -> one load and skip
  {
    int tc = *tailcnt; if (tc > TAILCAP) tc = TAILCAP;
    for (int r = 0; r < tc; r++) {
      if ((int)tailrec[2 * r + 1] != b) continue;
      unsigned rc = tailrec[2 * r];
      int tl = (int)(rc & 127u);
      if (tl == k0 || tl == k1) {
        int s = (int)(rc >> 7);
        if (USE_BF16) {
          uint4 v = xb4[s * 8 + l7];
          if (tl == k0) acc8_bf16(a0, v); else acc8_bf16(a1, v);
        } else {
          float4 u = x4[s * 16 + l7 * 2], w = x4[s * 16 + l7 * 2 + 1];
          if (tl == k0) acc8_f32(a0, u, w); else acc8_f32(a1, u, w);
        }
      }
    }
  }
  __syncthreads();  // all groups done reading sorted[] before overwrite

  // dump register acc into accum (union space)
  if (has0) {
#pragma unroll
    for (int j = 0; j < 8; j++) accum[k0 * ASTRIDE + 8 * l7 + j] = a0[j];
  }
  if (has1) {
#pragma unroll
    for (int j = 0; j < 8; j++) accum[k1 * ASTRIDE + 8 * l7 + j] = a1[j];
  }
  __syncthreads();

  // epilogue: out[n][lane] = norm[n] * sum_c accum[n][c] * W[c][lane]
  for (int i = wave; i < nn; i += 8) {
    int n = n0 + i;
    float a = accum[i * ASTRIDE + lane];   // lane holds channel `lane`
    float o = 0.0f;
#pragma unroll
    for (int c = 0; c < C; c++)
      o = fmaf(__shfl(a, c, 64), wreg[c], o);
    out[n * C + lane] = o * norm[n];
  }
}

extern "C" void kernel_launch(void* const* d_in, const int* in_sizes, int n_in,
                              void* d_out, int out_size, void* d_ws, size_t ws_size,
                              hipStream_t stream) {
  const float* x       = (const float*)d_in[0];
  const int*   sources = (const int*)d_in[1];
  const int*   targets = (const int*)d_in[2];
  const float* norm    = (const float*)d_in[3];
  const float* weight  = (const float*)d_in[4];
  float* out = (float*)d_out;

  int N = in_sizes[0] / C;     // 100000
  int E = in_sizes[1];         // 4000000
  int NB = (N + BN - 1) / BN;  // 782

  // ws layout: [xb (bf16, 12.8MB)] | cursor[NB] | tailcnt | tailrec[2*TAILCAP]
  //            | recs slabs [NB * slot]
  size_t availw = ws_size / 4;
  size_t xw = (size_t)N * C / 2;
  size_t fixedw = (size_t)NB + 1 + 2 * (size_t)TAILCAP;
  bool use_bf16; int slot;
  if (availw >= xw + fixedw + (size_t)NB * 8192) { use_bf16 = true; slot = 8192; }
  else if (availw >= xw + fixedw + (size_t)NB * 6144) { use_bf16 = true; slot = 6144; }
  else {
    // fp32 fallback: fixedw + NB*8192 words = 26.2MB (<= prior 28.8MB floor)
    use_bf16 = false;
    size_t s = (availw > fixedw) ? (availw - fixedw) / (size_t)NB : 0;
    slot = s > 8192 ? 8192 : (int)s;
  }

  unsigned* xb; int* cursor;
  if (use_bf16) {
    xb = (unsigned*)d_ws;                 // 16B-aligned block first
    cursor = (int*)d_ws + xw;
  } else {
    xb = nullptr;
    cursor = (int*)d_ws;
  }
  int* tailcnt = cursor + NB;
  unsigned* tailrec = (unsigned*)(tailcnt + 1);
  unsigned* recs = tailrec + 2 * (size_t)TAILCAP;

  int hb = (E + CHUNK2 - 1) / CHUNK2;  // 489
  int total8 = N * C / 8;              // 800000
  int cvtBlocks = use_bf16 ? (total8 + 511) / 512 : 0;

  init_kernel<<<(NB + 256) / 256, 256, 0, stream>>>(cursor, tailcnt, NB, slot);
  binfused_kernel<<<hb + cvtBlocks, 512, 0, stream>>>(
      sources, targets, cursor, tailcnt, tailrec, recs, x, xb,
      E, NB, slot, hb, total8);
  if (use_bf16) {
    sortgather_kernel<true><<<NB, 512, 0, stream>>>(
        x, xb, recs, cursor, tailcnt, tailrec, norm, weight, out, N, slot);
  } else {
    sortgather_kernel<false><<<NB, 512, 0, stream>>>(
        x, xb, recs, cursor, tailcnt, tailrec, norm, weight, out, N, slot);
  }
}